// Round 8
// baseline (106.851 us; speedup 1.0000x reference)
//
#include <hip/hip_runtime.h>
#include <hip/hip_bf16.h>
#include <math.h>

// GAT layer, V=8192, E=262144, D=128.
// out[i] = (S + sum_{distinct (i,j)} (exp(a_ij)-1)*hw[j]) / (V + sum (exp(a_ij)-1))
// a_ij = leakyrelu(s1[i]+s2[j], 0.2). Identities (R5, numerics-verified):
//   s1 = h @ (W^T att1), s2 = h @ (W^T att2), S = W @ colsum(h)
//
// R7 -> R8: kernels are a serial chain (~46us). Decouple s1/s2/S from the GEMM
// via the identities so R7's proven GEMM + scatter bodies run in ONE dispatch
// (k_mid: blocks 0-255 GEMM, 256-1279 scatter, 1280 S-finalize) -> k_mid ~=
// max(GEMM, scatter), scatter atomics hidden under GEMM VALU. k_pre computes
// u1/u2 redundantly per block (W is L2-hot), s1/s2 + colsum partials in one
// 4MB h sweep, zeroes cnt. k_row unchanged from R7.

#define V 8192
#define E 262144
#define D 128
#define NEG_SLOPE 0.2f
#define CAP 96    // bucket capacity/row; max expected degree ~55 (11-sigma safe)

#define FMA4(acc, hv, wv) { acc.x += (hv)*(wv).x; acc.y += (hv)*(wv).y; \
                            acc.z += (hv)*(wv).z; acc.w += (hv)*(wv).w; }

__device__ __forceinline__ unsigned short f2bf(float f) {   // RNE fp32->bf16
    unsigned u = __float_as_uint(f);
    return (unsigned short)((u + 0x7fffu + ((u >> 16) & 1u)) >> 16);
}
__device__ __forceinline__ float bf2f_low(int p) {          // low 16 bits -> float
    return __uint_as_float(((unsigned)p) << 16);
}

// ---------------- K0: u1/u2 -> s1/s2, colsum(h) partials, zero cnt ----------
// 256 blocks x 256 thr; 32 h-rows per block, one 4MB h sweep.
__global__ __launch_bounds__(256) void k_pre(const float* __restrict__ h,
                                             const float* __restrict__ W,
                                             const float* __restrict__ att,
                                             float* __restrict__ s1,
                                             float* __restrict__ s2,
                                             float* __restrict__ Pc,
                                             int* __restrict__ cnt) {
    __shared__ float atts[2 * D];
    __shared__ float us[2 * D];
    __shared__ float csc[4][D];
    int t = threadIdx.x, b = blockIdx.x;
    atts[t] = att[t];
    if (b < 32) cnt[b * 256 + t] = 0;     // zero cnt inline
    __syncthreads();
    if (t < D) {                          // u1/u2 = W^T att (redundant/block, L2-hot)
        float u1 = 0.f, u2 = 0.f;
        #pragma unroll 8
        for (int o = 0; o < D; ++o) {
            float wv = W[o * D + t];      // coalesced 512B/iter
            u1 += wv * atts[o];
            u2 += wv * atts[D + o];
        }
        us[t] = u1; us[D + t] = u2;
    }
    __syncthreads();
    int wv = t >> 6, lane = t & 63;
    float2 u1v = *(const float2*)&us[lane * 2];
    float2 u2v = *(const float2*)&us[D + lane * 2];
    int r0 = b * 32 + wv * 8;
    float cx = 0.f, cy = 0.f;
    #pragma unroll
    for (int r = 0; r < 8; ++r) {
        float2 hv = *(const float2*)&h[(r0 + r) * D + lane * 2];
        cx += hv.x; cy += hv.y;
        float p1 = hv.x * u1v.x + hv.y * u1v.y;
        float p2 = hv.x * u2v.x + hv.y * u2v.y;
        #pragma unroll
        for (int m = 32; m; m >>= 1) { p1 += __shfl_xor(p1, m); p2 += __shfl_xor(p2, m); }
        if (lane == 0) { s1[r0 + r] = p1; s2[r0 + r] = p2; }
    }
    *(float2*)&csc[wv][lane * 2] = make_float2(cx, cy);
    __syncthreads();
    if (t < D)
        Pc[b * D + t] = csc[0][t] + csc[1][t] + csc[2][t] + csc[3][t];
}

// ---------------- K1: GEMM (b<256) | scatter (256<=b<1280) | S (b==1280) ----
// GEMM body = R7's proven k_hw core; scatter body = R7's proven k_scatter.
__global__ __launch_bounds__(256) void k_mid(const float* __restrict__ h,
                                             const float* __restrict__ W,
                                             const int* __restrict__ ei,
                                             const float* __restrict__ s1,
                                             const float* __restrict__ s2,
                                             const float* __restrict__ Pc,
                                             unsigned short* __restrict__ hwb,
                                             float* __restrict__ S,
                                             int* __restrict__ cnt,
                                             int* __restrict__ bucket) {
    __shared__ float Wt[D * 132];      // 67.6KB; reserved by all roles (2 blocks/CU)
    int t = threadIdx.x, b = blockIdx.x;
    if (b < 256) {
        // ---- GEMM hw(bf16) = h @ W^T: 32 rows/block, 4 rows/thread ----
        for (int f4 = t; f4 < (D * D) / 4; f4 += 256) {
            int o = f4 >> 5, k = (f4 & 31) * 4;
            float4 wv = *(const float4*)&W[o * D + k];
            Wt[(k + 0) * 132 + o] = wv.x;
            Wt[(k + 1) * 132 + o] = wv.y;
            Wt[(k + 2) * 132 + o] = wv.z;
            Wt[(k + 3) * 132 + o] = wv.w;
        }
        __syncthreads();
        int c4 = (t & 31) * 4;
        int rq = t >> 5;
        int r0 = b * 32;
        float4 a0 = make_float4(0.f,0.f,0.f,0.f), a1 = a0, a2 = a0, a3 = a0;
        const float* h0p = &h[(r0 + rq     ) * D];
        const float* h1p = &h[(r0 + rq +  8) * D];
        const float* h2p = &h[(r0 + rq + 16) * D];
        const float* h3p = &h[(r0 + rq + 24) * D];
        #pragma unroll 4
        for (int kq = 0; kq < D; kq += 4) {
            float4 w0 = *(const float4*)&Wt[(kq + 0) * 132 + c4];
            float4 w1 = *(const float4*)&Wt[(kq + 1) * 132 + c4];
            float4 w2 = *(const float4*)&Wt[(kq + 2) * 132 + c4];
            float4 w3 = *(const float4*)&Wt[(kq + 3) * 132 + c4];
            float4 hv;
            hv = *(const float4*)&h0p[kq];
            FMA4(a0, hv.x, w0); FMA4(a0, hv.y, w1); FMA4(a0, hv.z, w2); FMA4(a0, hv.w, w3);
            hv = *(const float4*)&h1p[kq];
            FMA4(a1, hv.x, w0); FMA4(a1, hv.y, w1); FMA4(a1, hv.z, w2); FMA4(a1, hv.w, w3);
            hv = *(const float4*)&h2p[kq];
            FMA4(a2, hv.x, w0); FMA4(a2, hv.y, w1); FMA4(a2, hv.z, w2); FMA4(a2, hv.w, w3);
            hv = *(const float4*)&h3p[kq];
            FMA4(a3, hv.x, w0); FMA4(a3, hv.y, w1); FMA4(a3, hv.z, w2); FMA4(a3, hv.w, w3);
        }
        *(ushort4*)&hwb[(r0 + rq     ) * D + c4] = make_ushort4(f2bf(a0.x), f2bf(a0.y), f2bf(a0.z), f2bf(a0.w));
        *(ushort4*)&hwb[(r0 + rq +  8) * D + c4] = make_ushort4(f2bf(a1.x), f2bf(a1.y), f2bf(a1.z), f2bf(a1.w));
        *(ushort4*)&hwb[(r0 + rq + 16) * D + c4] = make_ushort4(f2bf(a2.x), f2bf(a2.y), f2bf(a2.z), f2bf(a2.w));
        *(ushort4*)&hwb[(r0 + rq + 24) * D + c4] = make_ushort4(f2bf(a3.x), f2bf(a3.y), f2bf(a3.z), f2bf(a3.w));
    } else if (b < 1280) {
        // ---- scatter: one edge/thread (R7 body) ----
        int g = (b - 256) * 256 + t;
        int src = ei[g];
        int dst = ei[E + g];
        float a = s1[src] + s2[dst];
        a = a > 0.f ? a : NEG_SLOPE * a;
        float w = expf(a) - 1.f;
        int pos = atomicAdd(&cnt[src], 1);
        if (pos < CAP)
            bucket[src * CAP + pos] = (dst << 16) | (int)f2bf(w);
    } else {
        // ---- S = W @ (sum of Pc partials) ----
        if (t < D) {
            float c = 0.f;
            #pragma unroll 8
            for (int bb = 0; bb < 256; ++bb) c += Pc[bb * D + t];   // coalesced
            Wt[t] = c;
        }
        __syncthreads();
        if (t < D) {
            float acc = 0.f;
            #pragma unroll
            for (int k = 0; k < D; k += 4) {
                float4 wv = *(const float4*)&W[t * D + k];   // L2-hot row stream
                float4 cv = *(const float4*)&Wt[k];
                acc += wv.x * cv.x + wv.y * cv.y + wv.z * cv.z + wv.w * cv.w;
            }
            S[t] = acc;
        }
    }
}

// ---------------- K2: per-row gather, 4 entries/iter, ballot dedup (R7) ------
__global__ __launch_bounds__(256) void k_row(const int* __restrict__ bucket,
                                             const int* __restrict__ cnt,
                                             const unsigned short* __restrict__ hwb,
                                             const float* __restrict__ S,
                                             float* __restrict__ out) {
    __shared__ int lb[4][CAP];
    int t = threadIdx.x;
    int wv = t >> 6, lane = t & 63;
    int row = blockIdx.x * 4 + wv;
    int deg = cnt[row];
    if (deg > CAP) deg = CAP;
    const int* bk = bucket + row * CAP;
    int e0 = bk[lane];
    int e1 = (lane < CAP - 64) ? bk[64 + lane] : 0;
    int p0 = (lane < deg)      ? e0 : (int)0xFFFF0000;
    int p1 = (64 + lane < deg) ? e1 : (int)0xFFFF0000;
    lb[wv][lane] = p0;
    if (lane < CAP - 64) lb[wv][64 + lane] = p1;
    int d0 = p0 >> 16;
    int d1 = p1 >> 16;
    int n0 = deg < 64 ? deg : 64;
    float accx = 0.f, accy = 0.f, dex = 0.f;
    const int* myb = lb[wv];
    int col2 = lane * 2;
    int j = 0;
    for (; j + 4 <= n0; j += 4) {
        int4 pq = *(const int4*)&myb[j];
        int dj0 = pq.x >> 16, dj1 = pq.y >> 16, dj2 = pq.z >> 16, dj3 = pq.w >> 16;
        unsigned hv0 = *(const unsigned*)&hwb[dj0 * D + col2];
        unsigned hv1 = *(const unsigned*)&hwb[dj1 * D + col2];
        unsigned hv2 = *(const unsigned*)&hwb[dj2 * D + col2];
        unsigned hv3 = *(const unsigned*)&hwb[dj3 * D + col2];
        unsigned long long m0 = __ballot(d0 == dj0);
        unsigned long long m1 = __ballot(d0 == dj1);
        unsigned long long m2 = __ballot(d0 == dj2);
        unsigned long long m3 = __ballot(d0 == dj3);
        float w0 = (m0 & ((1ull << (j + 0)) - 1ull)) ? 0.f : bf2f_low(pq.x);
        float w1 = (m1 & ((1ull << (j + 1)) - 1ull)) ? 0.f : bf2f_low(pq.y);
        float w2 = (m2 & ((1ull << (j + 2)) - 1ull)) ? 0.f : bf2f_low(pq.z);
        float w3 = (m3 & ((1ull << (j + 3)) - 1ull)) ? 0.f : bf2f_low(pq.w);
        accx += w0 * __uint_as_float(hv0 << 16);
        accy += w0 * __uint_as_float(hv0 & 0xFFFF0000u);
        accx += w1 * __uint_as_float(hv1 << 16);
        accy += w1 * __uint_as_float(hv1 & 0xFFFF0000u);
        accx += w2 * __uint_as_float(hv2 << 16);
        accy += w2 * __uint_as_float(hv2 & 0xFFFF0000u);
        accx += w3 * __uint_as_float(hv3 << 16);
        accy += w3 * __uint_as_float(hv3 & 0xFFFF0000u);
        dex += w0 + w1 + w2 + w3;
    }
    for (; j < n0; ++j) {
        int pj = myb[j];
        int dj = pj >> 16;
        float wj = bf2f_low(pj);
        unsigned long long m = __ballot(d0 == dj);
        if (m & ((1ull << j) - 1ull)) wj = 0.f;
        unsigned hv = *(const unsigned*)&hwb[dj * D + col2];
        accx += wj * __uint_as_float(hv << 16);
        accy += wj * __uint_as_float(hv & 0xFFFF0000u);
        dex += wj;
    }
    for (j = 64; j < deg; ++j) {
        int pj = myb[j];
        int dj = pj >> 16;
        float wj = bf2f_low(pj);
        unsigned long long m0 = __ballot(d0 == dj);
        unsigned long long m1 = __ballot(d1 == dj) & ((1ull << (j - 64)) - 1ull);
        if (m0 | m1) wj = 0.f;
        unsigned hv = *(const unsigned*)&hwb[dj * D + col2];
        accx += wj * __uint_as_float(hv << 16);
        accy += wj * __uint_as_float(hv & 0xFFFF0000u);
        dex += wj;
    }
    float inv = 1.f / ((float)V + dex);
    float2 s = *(const float2*)&S[col2];
    float2 o;
    o.x = (s.x + accx) * inv;
    o.y = (s.y + accy) * inv;
    *(float2*)&out[row * D + col2] = o;
}

extern "C" void kernel_launch(void* const* d_in, const int* in_sizes, int n_in,
                              void* d_out, int out_size, void* d_ws, size_t ws_size,
                              hipStream_t stream) {
    const float* h   = (const float*)d_in[0];
    const int*   ei  = (const int*)d_in[1];
    const float* W   = (const float*)d_in[2];
    const float* att = (const float*)d_in[3];
    float* out = (float*)d_out;

    char* ws = (char*)d_ws;
    // workspace layout (bytes):
    //   hwb    @ 0          2,097,152   (bf16 hw)
    //   s1     @ 2,097,152     32,768
    //   s2     @ 2,129,920     32,768
    //   S      @ 2,162,688        512
    //   cnt    @ 2,163,200     32,768
    //   bucket @ 2,195,968   3,145,728  (8192 * 96 * 4B packed)
    //   Pc     @ 5,341,696     131,072  (256 blocks * 128 colsum(h) partials)
    unsigned short* hwb = (unsigned short*)(ws);
    float* s1  = (float*)(ws + 2097152);
    float* s2  = (float*)(ws + 2129920);
    float* S   = (float*)(ws + 2162688);
    int*   cnt = (int*)(ws + 2163200);
    int*   bucket = (int*)(ws + 2195968);
    float* Pc  = (float*)(ws + 5341696);

    k_pre<<<256,  256, 0, stream>>>(h, W, att, s1, s2, Pc, cnt);
    k_mid<<<1281, 256, 0, stream>>>(h, W, ei, s1, s2, Pc, hwb, S, cnt, bucket);
    k_row<<<2048, 256, 0, stream>>>(bucket, cnt, hwb, S, out);
}

// Round 9
// 105.790 us; speedup vs baseline: 1.0100x; 1.0100x over previous
//
#include <hip/hip_runtime.h>
#include <hip/hip_bf16.h>
#include <math.h>

// GAT layer, V=8192, E=262144, D=128.
// out[i] = (S + sum_{distinct (i,j)} (exp(a_ij)-1)*hw[j]) / (V + sum (exp(a_ij)-1))
// a_ij = leakyrelu(s1[i]+s2[j], 0.2); s1/s2 = hw @ att halves; S = colsum(hw).
//
// R8 -> R9: dispatch restructuring exhausted (R8 neutral). Back to R7's proven
// 3-kernel shape; two contention/ILP fixes only:
//  (1) cnt padded to 1 counter / 64B line (was 16/line: 262K atomics over 512
//      lines = ~512 serialized per line; now 8192 lines x ~32).
//  (2) k_row 8 entries/iter (2x ds_read_b128 + 8 gathers in flight, was 4).
// Numerics identical to R7/R8 (absmax 2.441e-4).

#define V 8192
#define E 262144
#define D 128
#define NEG_SLOPE 0.2f
#define CAP 96     // bucket capacity/row; max expected degree ~55 (11-sigma safe)
#define CSTRIDE 16 // cnt padded: one counter per 64B cache line

#define FMA4(acc, hv, wv) { acc.x += (hv)*(wv).x; acc.y += (hv)*(wv).y; \
                            acc.z += (hv)*(wv).z; acc.w += (hv)*(wv).w; }

__device__ __forceinline__ unsigned short f2bf(float f) {   // RNE fp32->bf16
    unsigned u = __float_as_uint(f);
    return (unsigned short)((u + 0x7fffu + ((u >> 16) & 1u)) >> 16);
}
__device__ __forceinline__ float bf2f_low(int p) {          // low 16 bits -> float
    return __uint_as_float(((unsigned)p) << 16);
}

// ---------------- K1: hw(bf16) = h @ W^T, fused s1/s2 + colsum partials ------
// 256 blocks x 256 thr, 32 rows/block, 4 rows/thread (R7-proven core).
__global__ __launch_bounds__(256) void k_hw(const float* __restrict__ h,
                                            const float* __restrict__ W,
                                            const float* __restrict__ att,
                                            unsigned short* __restrict__ hwb,
                                            float* __restrict__ s1,
                                            float* __restrict__ s2,
                                            float* __restrict__ Pb,
                                            int* __restrict__ cnt) {
    __shared__ float Wt[D * 132];      // W transposed, pad 132
    __shared__ float atts[2 * D];
    __shared__ float scr[8 * D];       // colsum scratch
    int t = threadIdx.x, b = blockIdx.x;
    // zero padded cnt (V*CSTRIDE ints over 65536 threads -> 2 each)
    int g = b * 256 + t;
    cnt[g] = 0;
    cnt[g + V * CSTRIDE / 2] = 0;
    atts[t] = att[t];
    for (int f4 = t; f4 < (D * D) / 4; f4 += 256) {
        int o = f4 >> 5, k = (f4 & 31) * 4;
        float4 wv = *(const float4*)&W[o * D + k];   // coalesced 16B/lane
        Wt[(k + 0) * 132 + o] = wv.x;
        Wt[(k + 1) * 132 + o] = wv.y;
        Wt[(k + 2) * 132 + o] = wv.z;
        Wt[(k + 3) * 132 + o] = wv.w;
    }
    __syncthreads();

    int c4 = (t & 31) * 4;   // 4-col group
    int rq = t >> 5;         // 0..7; this thread: rows rq, rq+8, rq+16, rq+24
    int r0 = b * 32;
    float4 a0 = make_float4(0.f,0.f,0.f,0.f), a1 = a0, a2 = a0, a3 = a0;
    const float* h0p = &h[(r0 + rq     ) * D];
    const float* h1p = &h[(r0 + rq +  8) * D];
    const float* h2p = &h[(r0 + rq + 16) * D];
    const float* h3p = &h[(r0 + rq + 24) * D];
    #pragma unroll 4
    for (int kq = 0; kq < D; kq += 4) {
        float4 w0 = *(const float4*)&Wt[(kq + 0) * 132 + c4];
        float4 w1 = *(const float4*)&Wt[(kq + 1) * 132 + c4];
        float4 w2 = *(const float4*)&Wt[(kq + 2) * 132 + c4];
        float4 w3 = *(const float4*)&Wt[(kq + 3) * 132 + c4];
        float4 hv;
        hv = *(const float4*)&h0p[kq];   // wave-broadcast 16B (L1-hot stream)
        FMA4(a0, hv.x, w0); FMA4(a0, hv.y, w1); FMA4(a0, hv.z, w2); FMA4(a0, hv.w, w3);
        hv = *(const float4*)&h1p[kq];
        FMA4(a1, hv.x, w0); FMA4(a1, hv.y, w1); FMA4(a1, hv.z, w2); FMA4(a1, hv.w, w3);
        hv = *(const float4*)&h2p[kq];
        FMA4(a2, hv.x, w0); FMA4(a2, hv.y, w1); FMA4(a2, hv.z, w2); FMA4(a2, hv.w, w3);
        hv = *(const float4*)&h3p[kq];
        FMA4(a3, hv.x, w0); FMA4(a3, hv.y, w1); FMA4(a3, hv.z, w2); FMA4(a3, hv.w, w3);
    }
    *(ushort4*)&hwb[(r0 + rq     ) * D + c4] = make_ushort4(f2bf(a0.x), f2bf(a0.y), f2bf(a0.z), f2bf(a0.w));
    *(ushort4*)&hwb[(r0 + rq +  8) * D + c4] = make_ushort4(f2bf(a1.x), f2bf(a1.y), f2bf(a1.z), f2bf(a1.w));
    *(ushort4*)&hwb[(r0 + rq + 16) * D + c4] = make_ushort4(f2bf(a2.x), f2bf(a2.y), f2bf(a2.z), f2bf(a2.w));
    *(ushort4*)&hwb[(r0 + rq + 24) * D + c4] = make_ushort4(f2bf(a3.x), f2bf(a3.y), f2bf(a3.z), f2bf(a3.w));

    // fused s1/s2 (fp32, 32-lane group reduce), 4 rows
    float q1[4], q2[4];
    float4* accs[4] = {&a0, &a1, &a2, &a3};
    #pragma unroll
    for (int r = 0; r < 4; ++r) {
        float4 v = *accs[r];
        q1[r] = v.x * atts[c4] + v.y * atts[c4 + 1] + v.z * atts[c4 + 2] + v.w * atts[c4 + 3];
        q2[r] = v.x * atts[D + c4] + v.y * atts[D + c4 + 1] + v.z * atts[D + c4 + 2] + v.w * atts[D + c4 + 3];
    }
    #pragma unroll
    for (int m = 16; m; m >>= 1) {
        #pragma unroll
        for (int r = 0; r < 4; ++r) {
            q1[r] += __shfl_xor(q1[r], m);
            q2[r] += __shfl_xor(q2[r], m);
        }
    }
    if ((t & 31) == 0) {
        #pragma unroll
        for (int r = 0; r < 4; ++r) {
            s1[r0 + rq + r * 8] = q1[r];
            s2[r0 + rq + r * 8] = q2[r];
        }
    }

    // colsum partial: 4-row sums -> LDS -> plain store Pb[b][col] (no atomics)
    scr[rq * D + c4 + 0] = a0.x + a1.x + a2.x + a3.x;
    scr[rq * D + c4 + 1] = a0.y + a1.y + a2.y + a3.y;
    scr[rq * D + c4 + 2] = a0.z + a1.z + a2.z + a3.z;
    scr[rq * D + c4 + 3] = a0.w + a1.w + a2.w + a3.w;
    __syncthreads();
    if (t < D) {
        float s = 0.f;
        #pragma unroll
        for (int r = 0; r < 8; ++r) s += scr[r * D + t];
        Pb[b * D + t] = s;
    }
}

// ---------------- K2: scatter (b<1024, 1 edge/thr) | S-reduce (b==1024) -----
__global__ __launch_bounds__(256) void k_scatter(const int* __restrict__ ei,
                                                 const float* __restrict__ s1,
                                                 const float* __restrict__ s2,
                                                 int* __restrict__ cnt,
                                                 int* __restrict__ bucket,
                                                 const float* __restrict__ Pb,
                                                 float* __restrict__ S) {
    int b = blockIdx.x, t = threadIdx.x;
    if (b < 1024) {
        int g = b * 256 + t;               // one edge/thread: single atomic
        int src = ei[g];
        int dst = ei[E + g];
        float a = s1[src] + s2[dst];
        a = a > 0.f ? a : NEG_SLOPE * a;
        float w = expf(a) - 1.f;
        int pos = atomicAdd(&cnt[src * CSTRIDE], 1);   // private 64B line per row
        if (pos < CAP)
            bucket[src * CAP + pos] = (dst << 16) | (int)f2bf(w);  // 4B packed
    } else {
        __shared__ float red[256];
        int c = t & 127, half = t >> 7;
        float s = 0.f;
        #pragma unroll 4
        for (int r = half; r < 256; r += 2)
            s += Pb[r * D + c];
        red[t] = s;
        __syncthreads();
        if (t < D) S[t] = red[t] + red[D + t];
    }
}

// ---------------- K3: per-row gather, 8 entries/iter, ballot dedup -----------
// 2048 blocks x 256 thr, 1 row/wave. LDS-staged bucket, b128 broadcasts.
__global__ __launch_bounds__(256) void k_row(const int* __restrict__ bucket,
                                             const int* __restrict__ cnt,
                                             const unsigned short* __restrict__ hwb,
                                             const float* __restrict__ S,
                                             float* __restrict__ out) {
    __shared__ int lb[4][CAP];             // 1.5KB, 16B-aligned per wave
    int t = threadIdx.x;
    int wv = t >> 6, lane = t & 63;
    int row = blockIdx.x * 4 + wv;
    int deg = cnt[row * CSTRIDE];
    if (deg > CAP) deg = CAP;
    const int* bk = bucket + row * CAP;
    int e0 = bk[lane];
    int e1 = (lane < CAP - 64) ? bk[64 + lane] : 0;
    int p0 = (lane < deg)      ? e0 : (int)0xFFFF0000;   // invalid: d=-1, w=0
    int p1 = (64 + lane < deg) ? e1 : (int)0xFFFF0000;
    lb[wv][lane] = p0;
    if (lane < CAP - 64) lb[wv][64 + lane] = p1;
    int d0 = p0 >> 16;
    int d1 = p1 >> 16;
    int n0 = deg < 64 ? deg : 64;
    float accx = 0.f, accy = 0.f, dex = 0.f;
    const int* myb = lb[wv];
    int col2 = lane * 2;
    int j = 0;
    for (; j + 8 <= n0; j += 8) {
        int4 pa = *(const int4*)&myb[j];        // 2x ds_read_b128 broadcast
        int4 pb = *(const int4*)&myb[j + 4];
        int da0 = pa.x >> 16, da1 = pa.y >> 16, da2 = pa.z >> 16, da3 = pa.w >> 16;
        int db0 = pb.x >> 16, db1 = pb.y >> 16, db2 = pb.z >> 16, db3 = pb.w >> 16;
        unsigned ha0 = *(const unsigned*)&hwb[da0 * D + col2];   // 8 gathers in flight
        unsigned ha1 = *(const unsigned*)&hwb[da1 * D + col2];
        unsigned ha2 = *(const unsigned*)&hwb[da2 * D + col2];
        unsigned ha3 = *(const unsigned*)&hwb[da3 * D + col2];
        unsigned hb0 = *(const unsigned*)&hwb[db0 * D + col2];
        unsigned hb1 = *(const unsigned*)&hwb[db1 * D + col2];
        unsigned hb2 = *(const unsigned*)&hwb[db2 * D + col2];
        unsigned hb3 = *(const unsigned*)&hwb[db3 * D + col2];
        unsigned long long ma0 = __ballot(d0 == da0);
        unsigned long long ma1 = __ballot(d0 == da1);
        unsigned long long ma2 = __ballot(d0 == da2);
        unsigned long long ma3 = __ballot(d0 == da3);
        unsigned long long mb0 = __ballot(d0 == db0);
        unsigned long long mb1 = __ballot(d0 == db1);
        unsigned long long mb2 = __ballot(d0 == db2);
        unsigned long long mb3 = __ballot(d0 == db3);
        float wa0 = (ma0 & ((1ull << (j + 0)) - 1ull)) ? 0.f : bf2f_low(pa.x);
        float wa1 = (ma1 & ((1ull << (j + 1)) - 1ull)) ? 0.f : bf2f_low(pa.y);
        float wa2 = (ma2 & ((1ull << (j + 2)) - 1ull)) ? 0.f : bf2f_low(pa.z);
        float wa3 = (ma3 & ((1ull << (j + 3)) - 1ull)) ? 0.f : bf2f_low(pa.w);
        float wb0 = (mb0 & ((1ull << (j + 4)) - 1ull)) ? 0.f : bf2f_low(pb.x);
        float wb1 = (mb1 & ((1ull << (j + 5)) - 1ull)) ? 0.f : bf2f_low(pb.y);
        float wb2 = (mb2 & ((1ull << (j + 6)) - 1ull)) ? 0.f : bf2f_low(pb.z);
        float wb3 = (mb3 & ((1ull << (j + 7)) - 1ull)) ? 0.f : bf2f_low(pb.w);
        accx += wa0 * __uint_as_float(ha0 << 16);
        accy += wa0 * __uint_as_float(ha0 & 0xFFFF0000u);
        accx += wa1 * __uint_as_float(ha1 << 16);
        accy += wa1 * __uint_as_float(ha1 & 0xFFFF0000u);
        accx += wa2 * __uint_as_float(ha2 << 16);
        accy += wa2 * __uint_as_float(ha2 & 0xFFFF0000u);
        accx += wa3 * __uint_as_float(ha3 << 16);
        accy += wa3 * __uint_as_float(ha3 & 0xFFFF0000u);
        accx += wb0 * __uint_as_float(hb0 << 16);
        accy += wb0 * __uint_as_float(hb0 & 0xFFFF0000u);
        accx += wb1 * __uint_as_float(hb1 << 16);
        accy += wb1 * __uint_as_float(hb1 & 0xFFFF0000u);
        accx += wb2 * __uint_as_float(hb2 << 16);
        accy += wb2 * __uint_as_float(hb2 & 0xFFFF0000u);
        accx += wb3 * __uint_as_float(hb3 << 16);
        accy += wb3 * __uint_as_float(hb3 & 0xFFFF0000u);
        dex += wa0 + wa1 + wa2 + wa3 + wb0 + wb1 + wb2 + wb3;
    }
    for (; j < n0; ++j) {                   // tail (<8 entries)
        int pj = myb[j];
        int dj = pj >> 16;
        float wj = bf2f_low(pj);
        unsigned long long m = __ballot(d0 == dj);
        if (m & ((1ull << j) - 1ull)) wj = 0.f;
        unsigned hv = *(const unsigned*)&hwb[dj * D + col2];
        accx += wj * __uint_as_float(hv << 16);
        accy += wj * __uint_as_float(hv & 0xFFFF0000u);
        dex += wj;
    }
    for (j = 64; j < deg; ++j) {            // slots 64..95 (rare: deg>64)
        int pj = myb[j];
        int dj = pj >> 16;
        float wj = bf2f_low(pj);
        unsigned long long m0 = __ballot(d0 == dj);
        unsigned long long m1 = __ballot(d1 == dj) & ((1ull << (j - 64)) - 1ull);
        if (m0 | m1) wj = 0.f;
        unsigned hv = *(const unsigned*)&hwb[dj * D + col2];
        accx += wj * __uint_as_float(hv << 16);
        accy += wj * __uint_as_float(hv & 0xFFFF0000u);
        dex += wj;
    }
    float inv = 1.f / ((float)V + dex);
    float2 s = *(const float2*)&S[col2];
    float2 o;
    o.x = (s.x + accx) * inv;
    o.y = (s.y + accy) * inv;
    *(float2*)&out[row * D + col2] = o;
}

extern "C" void kernel_launch(void* const* d_in, const int* in_sizes, int n_in,
                              void* d_out, int out_size, void* d_ws, size_t ws_size,
                              hipStream_t stream) {
    const float* h   = (const float*)d_in[0];
    const int*   ei  = (const int*)d_in[1];
    const float* W   = (const float*)d_in[2];
    const float* att = (const float*)d_in[3];
    float* out = (float*)d_out;

    char* ws = (char*)d_ws;
    // workspace layout (bytes):
    //   hwb    @ 0          2,097,152   (bf16 hw)
    //   s1     @ 2,097,152     32,768
    //   s2     @ 2,129,920     32,768
    //   S      @ 2,162,688        512
    //   cnt    @ 2,163,200    524,288   (V counters padded to 64B lines)
    //   bucket @ 2,687,488  3,145,728   (8192 * 96 * 4B packed)
    //   Pb     @ 5,833,216    131,072   (256 blocks * 128 colsum partials)
    unsigned short* hwb = (unsigned short*)(ws);
    float* s1  = (float*)(ws + 2097152);
    float* s2  = (float*)(ws + 2129920);
    float* S   = (float*)(ws + 2162688);
    int*   cnt = (int*)(ws + 2163200);
    int*   bucket = (int*)(ws + 2687488);
    float* Pb  = (float*)(ws + 5833216);

    k_hw     <<<256,  256, 0, stream>>>(h, W, att, hwb, s1, s2, Pb, cnt);
    k_scatter<<<1025, 256, 0, stream>>>(ei, s1, s2, cnt, bucket, Pb, S);
    k_row    <<<2048, 256, 0, stream>>>(bucket, cnt, hwb, S, out);
}